// Round 8
// baseline (232.720 us; speedup 1.0000x reference)
//
#include <hip/hip_runtime.h>

// ---------------------------------------------------------------------------
// SelfMultiheadAttn fwd: T=2048, B=4, E=1024, H=16, D=64, causal.
// Round 16: abandon 8-phase (r14: 72us, r15: 83us — at 1 block/CU the 16
// lockstep barriers/iter cost ~1500cy each vs 250cy of work; K=1024 too short
// to amortize). Back to the proven m97 2-barrier structure AT ITS BEST TILE:
// gemm256 retiled 256x128 -> 128x128 (ladder: 128^2=912 TF vs 128x256=823).
//   grid (24,64) = 1536 blocks = 6 uniform rounds, 3 blocks/CU (32KB LDS),
//   ~12 waves/CU. K-loop = gemm128's verbatim. Epilogues re-derived for the
//   64x64-per-wave layout (wm=(w&1)*64, wn=(w>>1)*64):
//   Q/K scatter same algebra; V via per-wave 64dd x 16t transpose (stride-24
//   pad, 16B stores, LGKM0-guarded WAR).
// Rest = round-13 baseline (223.8us): attn 8-wave counted-vmcnt, gemm128,
// merged cvt, exp2-folded W_q.
// ---------------------------------------------------------------------------

typedef float  f32x4  __attribute__((ext_vector_type(4)));
typedef short  s16x8  __attribute__((ext_vector_type(8)));
typedef __bf16 bf16x8 __attribute__((ext_vector_type(8)));

#define T_DIM 2048
#define B_DIM 4
#define E_DIM 1024
#define PLANE (T_DIM * 64)   // elements per (which,b,h) plane

#define VMC(N) asm volatile("s_waitcnt vmcnt(" #N ")" ::: "memory")
#define LGKM0() asm volatile("s_waitcnt lgkmcnt(0)" ::: "memory")
#define BAR() __builtin_amdgcn_s_barrier()

__device__ inline unsigned short f2bf(float f) {
  return (unsigned short)((__builtin_bit_cast(unsigned int, f) + 0x8000u) >> 16);
}

__device__ inline f32x4 mfma16(s16x8 a, s16x8 b, f32x4 c) {
  return __builtin_amdgcn_mfma_f32_16x16x32_bf16(
      __builtin_bit_cast(bf16x8, a), __builtin_bit_cast(bf16x8, b), c, 0, 0, 0);
}

__device__ inline void gl2lds16(const unsigned short* g, unsigned short* l) {
  __builtin_amdgcn_global_load_lds(
      (__attribute__((address_space(1))) unsigned int*)g,
      (__attribute__((address_space(3))) unsigned int*)l, 16, 0, 0);
}

// pack hi16(a) | hi16(b)<<16  (bf16 truncation) in one v_perm
__device__ inline unsigned packbf(float a, float b) {
  return __builtin_amdgcn_perm(__builtin_bit_cast(unsigned, b),
                               __builtin_bit_cast(unsigned, a), 0x07060302u);
}

// ---------------------------------------------------------------------------
// Merged input conversion: blocks [0,8192) query -> xb; [8192,11264) W_in ->
// winb (first E*E/4 float4s carry the Q scale); [11264,12288) W_out -> wob
// (skipped when do_wout==0; fallback path converts W_out after attn).
// ---------------------------------------------------------------------------
__global__ __launch_bounds__(256)
void cvt_all(const float* __restrict__ q, const float* __restrict__ wi,
             const float* __restrict__ wo, unsigned short* __restrict__ xb,
             unsigned short* __restrict__ wib, unsigned short* __restrict__ wob,
             float qs, int do_wout) {
  int blk = blockIdx.x;
  const float* src;
  unsigned short* dst;
  int i;
  float sc = 1.0f;
  if (blk < 8192) {
    src = q; dst = xb; i = blk * 256 + threadIdx.x;
  } else if (blk < 11264) {
    src = wi; dst = wib; i = (blk - 8192) * 256 + threadIdx.x;
    if (i < (E_DIM * E_DIM / 4)) sc = qs;
  } else {
    if (!do_wout) return;
    src = wo; dst = wob; i = (blk - 11264) * 256 + threadIdx.x;
  }
  float4 v = ((const float4*)src)[i];
  ushort4 o;
  o.x = f2bf(v.x * sc); o.y = f2bf(v.y * sc);
  o.z = f2bf(v.z * sc); o.w = f2bf(v.w * sc);
  ((ushort4*)dst)[i] = o;
}

__global__ __launch_bounds__(256)
void cvt_bf16(const float* __restrict__ in, unsigned short* __restrict__ out,
              int n4) {
  int i = blockIdx.x * 256 + threadIdx.x;
  if (i >= n4) return;
  float4 v = ((const float4*)in)[i];
  ushort4 o;
  o.x = f2bf(v.x); o.y = f2bf(v.y); o.z = f2bf(v.z); o.w = f2bf(v.w);
  ((ushort4*)out)[i] = o;
}

// ---------------------------------------------------------------------------
// gemm_qkv: C[m,n]=sum_k A[m,k]*B[n,k]; 128x128 tile, m97 2-barrier structure
// (= gemm128's loop). Epilogue scatters into the qkv layout; V block via a
// per-wave LDS transpose (As reused after the final barrier).
// ---------------------------------------------------------------------------
__global__ __launch_bounds__(256)
void gemm_qkv(const unsigned short* __restrict__ A,
              const unsigned short* __restrict__ Bw,
              unsigned short* __restrict__ Cq, int K) {
  __shared__ __attribute__((aligned(16))) unsigned short As[128 * 64];
  __shared__ __attribute__((aligned(16))) unsigned short Bs[128 * 64];

  const int tid = threadIdx.x, lane = tid & 63, w = tid >> 6;
  const int row16 = lane & 15, quad = lane >> 4;
  const int m0 = blockIdx.y * 128, n0 = blockIdx.x * 128;
  const int wm = (w & 1) * 64, wn = (w >> 1) * 64;
  const int srow = lane >> 3;
  const int jsw = (lane & 7) ^ srow;
  const int sw7 = row16 & 7;

  f32x4 acc[4][4];
  for (int i = 0; i < 4; ++i)
    for (int j = 0; j < 4; ++j) acc[i][j] = (f32x4){0.f, 0.f, 0.f, 0.f};

  for (int k0 = 0; k0 < K; k0 += 64) {
    for (int i = 0; i < 4; ++i) {
      int ia = i * 4 + w;
      int r = ia * 8 + srow;
      gl2lds16(A  + (size_t)(m0 + r) * K + k0 + jsw * 8, &As[ia * 512]);
      gl2lds16(Bw + (size_t)(n0 + r) * K + k0 + jsw * 8, &Bs[ia * 512]);
    }
    __syncthreads();
    for (int kk = 0; kk < 2; ++kk) {
      s16x8 af[4], bfr[4];
      for (int mi = 0; mi < 4; ++mi)
        af[mi] = *(const s16x8*)&As[(wm + mi * 16 + row16) * 64 +
                                    (((kk * 4 + quad) ^ sw7) * 8)];
      for (int ni = 0; ni < 4; ++ni)
        bfr[ni] = *(const s16x8*)&Bs[(wn + ni * 16 + row16) * 64 +
                                     (((kk * 4 + quad) ^ sw7) * 8)];
      for (int mi = 0; mi < 4; ++mi)
        for (int ni = 0; ni < 4; ++ni)
          acc[mi][ni] = mfma16(af[mi], bfr[ni], acc[mi][ni]);
    }
    __syncthreads();
  }

  if (n0 >= 2048) {
    // V block. Wave w covers head hw = ((n0-2048)>>6) + (w>>1) (64 cols) and
    // 64 m-rows -> 16 t x 4 b (t-base tg0 = m0/4 + (w&1)*16).
    // Per-wave transpose: tb[64 dd][16 tl], stride 24 (pad).
    const int hw = ((n0 - 2048) >> 6) + (w >> 1);
    const int tg0 = (m0 >> 2) + (w & 1) * 16;
    unsigned short* tb = &As[w * 1536];
    for (int bb = 0; bb < 4; ++bb) {
#pragma unroll
      for (int mi = 0; mi < 4; ++mi)
#pragma unroll
        for (int ni = 0; ni < 4; ++ni)
          tb[(ni * 16 + row16) * 24 + mi * 4 + quad] = f2bf(acc[mi][ni][bb]);
      LGKM0();
      unsigned short* vp = Cq + (size_t)(128 + bb * 16 + hw) * PLANE;
#pragma unroll
      for (int it = 0; it < 2; ++it) {
        int dd = it * 32 + (lane >> 1);
        int tl = (lane & 1) * 8;
        s16x8 v = *(const s16x8*)&tb[dd * 24 + tl];
        *(s16x8*)(vp + (size_t)dd * T_DIM + tg0 + tl) = v;
      }
      LGKM0();  // WAR before next bb overwrites tb
    }
  } else {
    // Q/K blocks: [t][d] scatter (32B runs across row16 lanes)
    for (int mi = 0; mi < 4; ++mi)
      for (int ni = 0; ni < 4; ++ni)
        for (int r = 0; r < 4; ++r) {
          int m = m0 + wm + mi * 16 + quad * 4 + r;
          int n = n0 + wn + ni * 16 + row16;
          int t = m >> 2, bb = m & 3;
          int which = n >> 10, hh = (n >> 6) & 15, dd = n & 63;
          Cq[(size_t)(which * 64 + bb * 16 + hh) * PLANE + (size_t)t * 64 + dd] =
              f2bf(acc[mi][ni][r]);
        }
  }
}

// ---------------------------------------------------------------------------
// gemm128 (m97 structure, swizzled LDS), fp32 output — out-proj.
// ---------------------------------------------------------------------------
__global__ __launch_bounds__(256)
void gemm128(const unsigned short* __restrict__ A,
             const unsigned short* __restrict__ Bw,
             float* __restrict__ Cf, int N, int K) {
  __shared__ __attribute__((aligned(16))) unsigned short As[128 * 64];
  __shared__ __attribute__((aligned(16))) unsigned short Bs[128 * 64];

  const int tid = threadIdx.x, lane = tid & 63, w = tid >> 6;
  const int row16 = lane & 15, quad = lane >> 4;
  const int m0 = blockIdx.y * 128, n0 = blockIdx.x * 128;
  const int wm = (w & 1) * 64, wn = (w >> 1) * 64;
  const int srow = lane >> 3;
  const int jsw = (lane & 7) ^ srow;
  const int sw7 = row16 & 7;

  f32x4 acc[4][4];
  for (int i = 0; i < 4; ++i)
    for (int j = 0; j < 4; ++j) acc[i][j] = (f32x4){0.f, 0.f, 0.f, 0.f};

  for (int k0 = 0; k0 < K; k0 += 64) {
    for (int i = 0; i < 4; ++i) {
      int ia = i * 4 + w;
      int r = ia * 8 + srow;
      gl2lds16(A  + (size_t)(m0 + r) * K + k0 + jsw * 8, &As[ia * 512]);
      gl2lds16(Bw + (size_t)(n0 + r) * K + k0 + jsw * 8, &Bs[ia * 512]);
    }
    __syncthreads();
    for (int kk = 0; kk < 2; ++kk) {
      s16x8 af[4], bfr[4];
      for (int mi = 0; mi < 4; ++mi)
        af[mi] = *(const s16x8*)&As[(wm + mi * 16 + row16) * 64 +
                                    (((kk * 4 + quad) ^ sw7) * 8)];
      for (int ni = 0; ni < 4; ++ni)
        bfr[ni] = *(const s16x8*)&Bs[(wn + ni * 16 + row16) * 64 +
                                     (((kk * 4 + quad) ^ sw7) * 8)];
      for (int mi = 0; mi < 4; ++mi)
        for (int ni = 0; ni < 4; ++ni)
          acc[mi][ni] = mfma16(af[mi], bfr[ni], acc[mi][ni]);
    }
    __syncthreads();
  }

  for (int mi = 0; mi < 4; ++mi)
    for (int ni = 0; ni < 4; ++ni)
      for (int r = 0; r < 4; ++r) {
        int m = m0 + wm + mi * 16 + quad * 4 + r;
        int n = n0 + wn + ni * 16 + row16;
        Cf[(size_t)m * N + n] = acc[mi][ni][r];
      }
}

// ---------------------------------------------------------------------------
// Flash attention (round-13 version). grid = (64, 8), 512 threads (8 waves).
// ---------------------------------------------------------------------------
__global__ __launch_bounds__(512, 4)
void attn_fwd(const unsigned short* __restrict__ qkv,
              unsigned short* __restrict__ ctx) {
  __shared__ __attribute__((aligned(16))) unsigned short Ks[2][4096];
  __shared__ __attribute__((aligned(16))) unsigned short Vs[2][4096];
  __shared__ __attribute__((aligned(16))) unsigned short Ps[8][1024];

  const int tid = threadIdx.x, lane = tid & 63, w = tid >> 6;  // w 0..7
  const int row16 = lane & 15, quad = lane >> 4;
  const int bh = blockIdx.x;     // 0..63
  const int p  = blockIdx.y;     // 0..7
  const int b = bh >> 4, h = bh & 15;

  const unsigned short* Qg = qkv + (size_t)bh * PLANE;          // [t][d]
  const unsigned short* Kg = qkv + (size_t)(64 + bh) * PLANE;   // [t][d]
  const unsigned short* Vt = qkv + (size_t)(128 + bh) * PLANE;  // [d][t]

  const int r8 = lane >> 3;
  const int jsw = (lane & 7) ^ r8;
  const int sw7 = row16 & 7;

  auto stage = [&](int c, int buf) {   // 2 DMA issues per wave per call
    int r = w * 8 + r8;                // 8 waves cover all 64 rows
    gl2lds16(Kg + (size_t)(c * 64 + r) * 64 + jsw * 8, &Ks[buf][w * 512]);
    gl2lds16(Vt + (size_t)r * T_DIM + c * 64 + jsw * 8, &Vs[buf][w * 512]);
  };

  for (int half = 0; half < 2; ++half) {
    const int qt = half ? p : (15 - p);
    const int q0w = qt * 128 + w * 16;
    const int cmax = 2 * qt + 1;           // >= 1 always
    const int dc = 2 * qt + (w >> 2);

    s16x8 qb[2];
    for (int s = 0; s < 2; ++s)
      qb[s] = *(const s16x8*)(Qg + (size_t)(q0w + row16) * 64 + s * 32 +
                              quad * 8);

    f32x4 O[4];
    for (int md = 0; md < 4; ++md) O[md] = (f32x4){0.f, 0.f, 0.f, 0.f};
    float lp = 0.f;

    // 2-deep prologue (final end-of-iter barrier of prev half cleared WAR)
    stage(0, 0);
    stage(1, 1);

    for (int c = 0; c <= cmax; ++c) {
      const int buf = c & 1;
      // Counted wait: own chunk c landed; chunk c+1 stays in flight across
      // the barrier (T4 — drain to 0 only on the final iter).
      if (c < cmax) VMC(2);
      else          VMC(0);
      BAR();  // all waves' chunk c landed

      if (c <= dc) {
        f32x4 S[4];
        for (int nt = 0; nt < 4; ++nt) S[nt] = (f32x4){0.f, 0.f, 0.f, 0.f};
        __builtin_amdgcn_s_setprio(1);
        for (int nt = 0; nt < 4; ++nt)
          for (int s = 0; s < 2; ++s) {
            s16x8 ka = *(const s16x8*)&Ks[buf][(nt * 16 + row16) * 64 +
                                              (((s * 4 + quad) ^ sw7) * 8)];
            S[nt] = mfma16(ka, qb[s], S[nt]);
          }
        __builtin_amdgcn_s_setprio(0);

        // softmax numerator + pack into Ps; diag path carries the causal mask
        const int qg = q0w + row16;
        auto softmax_store = [&](bool diagm) {
          for (int nt = 0; nt < 4; ++nt) {
            float pv[4];
            for (int r = 0; r < 4; ++r) {
              pv[r] = __builtin_amdgcn_exp2f(S[nt][r]);
              if (diagm && (c * 64 + nt * 16 + quad * 4 + r) > qg) pv[r] = 0.f;
              lp += pv[r];
            }
            int pos = (nt * 2 + (quad >> 1)) ^ sw7;
            *(uint2*)&Ps[w][row16 * 64 + pos * 8 + (quad & 1) * 4] =
                make_uint2(packbf(pv[0], pv[1]), packbf(pv[2], pv[3]));
          }
        };
        if (c == dc) softmax_store(true); else softmax_store(false);
        LGKM0();  // Ps is per-wave

        __builtin_amdgcn_s_setprio(1);
        for (int sk = 0; sk < 2; ++sk) {
          s16x8 pb = *(const s16x8*)&Ps[w][row16 * 64 +
                                          (((sk * 4 + quad) ^ sw7) * 8)];
          for (int md = 0; md < 4; ++md) {
            s16x8 va = *(const s16x8*)&Vs[buf][(md * 16 + row16) * 64 +
                                              (((sk * 4 + quad) ^ sw7) * 8)];
            O[md] = mfma16(va, pb, O[md]);
          }
        }
        __builtin_amdgcn_s_setprio(0);
      }

      BAR();  // all waves done reading buf -> WAR clear
      if (c + 2 <= cmax) stage(c + 2, buf);
    }

    {
      float s = lp;
      s += __shfl_xor(s, 16);
      s += __shfl_xor(s, 32);
      float inv = 1.f / s;
      const int t = q0w + row16;
      for (int md = 0; md < 4; ++md) {
        unsigned lo = packbf(O[md][0] * inv, O[md][1] * inv);
        unsigned hi = packbf(O[md][2] * inv, O[md][3] * inv);
        *(uint2*)&ctx[((size_t)t * B_DIM + b) * E_DIM + h * 64 + md * 16 +
                      quad * 4] = make_uint2(lo, hi);
      }
    }
  }
}

// ---------------------------------------------------------------------------
extern "C" void kernel_launch(void* const* d_in, const int* in_sizes, int n_in,
                              void* d_out, int out_size, void* d_ws,
                              size_t ws_size, hipStream_t stream) {
  const float* query = (const float*)d_in[0];  // [T,B,E] = [8192,1024]
  const float* win   = (const float*)d_in[1];  // [3072,1024]
  const float* wout  = (const float*)d_in[2];  // [1024,1024]
  float* out = (float*)d_out;

  const size_t qkv_el = (size_t)3 * 64 * PLANE;   // 25,165,824 ushort
  const size_t ctx_el = (size_t)T_DIM * B_DIM * E_DIM;  // 8,388,608 ushort

  unsigned short* qkvb = (unsigned short*)d_ws;
  unsigned short* ctxb = qkvb + qkv_el;
  unsigned short* xb   = ctxb;                   // dies before ctx written
  unsigned short* winb = (unsigned short*)d_out; // d_out scratch until gemm2

  // W_out bf16: fresh ws region after ctx when it fits (enables upfront
  // merged cvt); else reuse qkvb after attn (old path).
  const bool big_ws = ws_size >= (qkv_el + ctx_el + (size_t)E_DIM * E_DIM) * 2;
  unsigned short* woutb = big_ws ? (ctxb + ctx_el) : qkvb;

  // 0.125 (1/sqrt(D)) * log2(e): folded into W_q so attn uses exp2 directly.
  const float QSCALE = 0.18033688011112042f;

  cvt_all<<<big_ws ? 12288 : 11264, 256, 0, stream>>>(
      query, win, wout, xb, winb, woutb, QSCALE, big_ws ? 1 : 0);
  gemm_qkv<<<dim3(3072 / 128, 8192 / 128), 256, 0, stream>>>(xb, winb, qkvb,
                                                             1024);
  attn_fwd<<<dim3(64, 8), 512, 0, stream>>>(qkvb, ctxb);
  if (!big_ws)
    cvt_bf16<<<1024, 256, 0, stream>>>(wout, woutb, (1024 * 1024) / 4);
  gemm128<<<dim3(8, 64), 256, 0, stream>>>(ctxb, woutb, out, 1024, 1024);
}

// Round 11
// 227.308 us; speedup vs baseline: 1.0238x; 1.0238x over previous
//
#include <hip/hip_runtime.h>

// ---------------------------------------------------------------------------
// SelfMultiheadAttn fwd: T=2048, B=4, E=1024, H=16, D=64, causal.
// Round 19: epilogues reverted to round-16 known-pass versions (the Q/K
// LDS-repack kernel failed 4 container attempts across rounds 9-10; audit
// clean but not worth a 3rd gamble, and its VALU share is only ~12%).
// New: gemm_qkv K-loop DOUBLE-BUFFERED with counted vmcnt — the exact
// session-proven attn template (round 10: +46%): 2-deep As/Bs (64KB LDS,
// 2 blocks/CU), per-iter VMC(8) (tile k landed, k+1 in flight; VMC(0) only
// final), raw BAR before compute + BAR after compute, stage(k+2) after the
// post-compute barrier. Removes the per-K-step __syncthreads vmcnt(0) drain
// that exposed ~900cy DMA latency 16x per block at only 3 blocks/CU.
// NOT the failed 8-phase (that was 16 barriers/iter @ 1 blk/CU).
// Kept: 128^2 tile, scatter Q/K epilogue + V-transpose epilogue (r16
// known-pass), attn 8-wave counted-vmcnt, gemm128, merged cvt, exp2 W_q.
// ---------------------------------------------------------------------------

typedef float  f32x4  __attribute__((ext_vector_type(4)));
typedef short  s16x8  __attribute__((ext_vector_type(8)));
typedef __bf16 bf16x8 __attribute__((ext_vector_type(8)));

#define T_DIM 2048
#define B_DIM 4
#define E_DIM 1024
#define PLANE (T_DIM * 64)   // elements per (which,b,h) plane

#define VMC(N) asm volatile("s_waitcnt vmcnt(" #N ")" ::: "memory")
#define LGKM0() asm volatile("s_waitcnt lgkmcnt(0)" ::: "memory")
#define BAR() __builtin_amdgcn_s_barrier()

__device__ inline unsigned short f2bf(float f) {
  return (unsigned short)((__builtin_bit_cast(unsigned int, f) + 0x8000u) >> 16);
}

__device__ inline f32x4 mfma16(s16x8 a, s16x8 b, f32x4 c) {
  return __builtin_amdgcn_mfma_f32_16x16x32_bf16(
      __builtin_bit_cast(bf16x8, a), __builtin_bit_cast(bf16x8, b), c, 0, 0, 0);
}

__device__ inline void gl2lds16(const unsigned short* g, unsigned short* l) {
  __builtin_amdgcn_global_load_lds(
      (__attribute__((address_space(1))) unsigned int*)g,
      (__attribute__((address_space(3))) unsigned int*)l, 16, 0, 0);
}

// pack hi16(a) | hi16(b)<<16  (bf16 truncation) in one v_perm
__device__ inline unsigned packbf(float a, float b) {
  return __builtin_amdgcn_perm(__builtin_bit_cast(unsigned, b),
                               __builtin_bit_cast(unsigned, a), 0x07060302u);
}

// ---------------------------------------------------------------------------
// Merged input conversion: blocks [0,8192) query -> xb; [8192,11264) W_in ->
// winb (first E*E/4 float4s carry the Q scale); [11264,12288) W_out -> wob
// (skipped when do_wout==0; fallback path converts W_out after attn).
// ---------------------------------------------------------------------------
__global__ __launch_bounds__(256)
void cvt_all(const float* __restrict__ q, const float* __restrict__ wi,
             const float* __restrict__ wo, unsigned short* __restrict__ xb,
             unsigned short* __restrict__ wib, unsigned short* __restrict__ wob,
             float qs, int do_wout) {
  int blk = blockIdx.x;
  const float* src;
  unsigned short* dst;
  int i;
  float sc = 1.0f;
  if (blk < 8192) {
    src = q; dst = xb; i = blk * 256 + threadIdx.x;
  } else if (blk < 11264) {
    src = wi; dst = wib; i = (blk - 8192) * 256 + threadIdx.x;
    if (i < (E_DIM * E_DIM / 4)) sc = qs;
  } else {
    if (!do_wout) return;
    src = wo; dst = wob; i = (blk - 11264) * 256 + threadIdx.x;
  }
  float4 v = ((const float4*)src)[i];
  ushort4 o;
  o.x = f2bf(v.x * sc); o.y = f2bf(v.y * sc);
  o.z = f2bf(v.z * sc); o.w = f2bf(v.w * sc);
  ((ushort4*)dst)[i] = o;
}

__global__ __launch_bounds__(256)
void cvt_bf16(const float* __restrict__ in, unsigned short* __restrict__ out,
              int n4) {
  int i = blockIdx.x * 256 + threadIdx.x;
  if (i >= n4) return;
  float4 v = ((const float4*)in)[i];
  ushort4 o;
  o.x = f2bf(v.x); o.y = f2bf(v.y); o.z = f2bf(v.z); o.w = f2bf(v.w);
  ((ushort4*)out)[i] = o;
}

// ---------------------------------------------------------------------------
// gemm_qkv: C[m,n]=sum_k A[m,k]*B[n,k]; 128x128 tile; K-loop double-buffered
// with counted vmcnt (attn template). Epilogue -> qkv scatter (round-16
// version); V block via per-wave LDS transpose.
// ---------------------------------------------------------------------------
__global__ __launch_bounds__(256)
void gemm_qkv(const unsigned short* __restrict__ A,
              const unsigned short* __restrict__ Bw,
              unsigned short* __restrict__ Cq, int K) {
  __shared__ __attribute__((aligned(16))) unsigned short As[2][8192];
  __shared__ __attribute__((aligned(16))) unsigned short Bs[2][8192];

  const int tid = threadIdx.x, lane = tid & 63, w = tid >> 6;
  const int row16 = lane & 15, quad = lane >> 4;
  const int m0 = blockIdx.y * 128, n0 = blockIdx.x * 128;
  const int wm = (w & 1) * 64, wn = (w >> 1) * 64;
  const int srow = lane >> 3;
  const int jsw = (lane & 7) ^ srow;
  const int sw7 = row16 & 7;

  f32x4 acc[4][4];
  for (int i = 0; i < 4; ++i)
    for (int j = 0; j < 4; ++j) acc[i][j] = (f32x4){0.f, 0.f, 0.f, 0.f};

  auto stage = [&](int kt, int buf) {   // 8 DMA issues per wave
#pragma unroll
    for (int i = 0; i < 4; ++i) {
      int ia = i * 4 + w;
      int r = ia * 8 + srow;
      gl2lds16(A  + (size_t)(m0 + r) * K + kt * 64 + jsw * 8,
               &As[buf][ia * 512]);
      gl2lds16(Bw + (size_t)(n0 + r) * K + kt * 64 + jsw * 8,
               &Bs[buf][ia * 512]);
    }
  };

  const int NT = K / 64;  // 16 K-tiles
  stage(0, 0);
  stage(1, 1);

  for (int kt = 0; kt < NT; ++kt) {
    const int buf = kt & 1;
    // Counted wait: tile kt's 8 loads landed; tile kt+1's 8 stay in flight
    // across the barrier (drain to 0 only on the final iter).
    if (kt < NT - 1) VMC(8);
    else             VMC(0);
    BAR();  // all waves' tile kt landed

    for (int kk = 0; kk < 2; ++kk) {
      s16x8 af[4], bfr[4];
      for (int mi = 0; mi < 4; ++mi)
        af[mi] = *(const s16x8*)&As[buf][(wm + mi * 16 + row16) * 64 +
                                         (((kk * 4 + quad) ^ sw7) * 8)];
      for (int ni = 0; ni < 4; ++ni)
        bfr[ni] = *(const s16x8*)&Bs[buf][(wn + ni * 16 + row16) * 64 +
                                          (((kk * 4 + quad) ^ sw7) * 8)];
      for (int mi = 0; mi < 4; ++mi)
        for (int ni = 0; ni < 4; ++ni)
          acc[mi][ni] = mfma16(af[mi], bfr[ni], acc[mi][ni]);
    }

    BAR();  // all waves done reading buf -> WAR clear for re-staging
    if (kt + 2 < NT) stage(kt + 2, buf);
  }

  if (n0 >= 2048) {
    // V block. Wave w covers head hw = ((n0-2048)>>6) + (w>>1) (64 cols) and
    // 64 m-rows -> 16 t x 4 b (t-base tg0 = m0/4 + (w&1)*16).
    // Per-wave transpose: tb[64 dd][16 tl], stride 24 (pad).
    const int hw = ((n0 - 2048) >> 6) + (w >> 1);
    const int tg0 = (m0 >> 2) + (w & 1) * 16;
    unsigned short* tb = &As[0][0] + w * 1536;
    for (int bb = 0; bb < 4; ++bb) {
#pragma unroll
      for (int mi = 0; mi < 4; ++mi)
#pragma unroll
        for (int ni = 0; ni < 4; ++ni)
          tb[(ni * 16 + row16) * 24 + mi * 4 + quad] = f2bf(acc[mi][ni][bb]);
      LGKM0();
      unsigned short* vp = Cq + (size_t)(128 + bb * 16 + hw) * PLANE;
#pragma unroll
      for (int it = 0; it < 2; ++it) {
        int dd = it * 32 + (lane >> 1);
        int tl = (lane & 1) * 8;
        s16x8 v = *(const s16x8*)&tb[dd * 24 + tl];
        *(s16x8*)(vp + (size_t)dd * T_DIM + tg0 + tl) = v;
      }
      LGKM0();  // WAR before next bb overwrites tb
    }
  } else {
    // Q/K blocks: [t][d] scatter (32B runs across row16 lanes)
    for (int mi = 0; mi < 4; ++mi)
      for (int ni = 0; ni < 4; ++ni)
        for (int r = 0; r < 4; ++r) {
          int m = m0 + wm + mi * 16 + quad * 4 + r;
          int n = n0 + wn + ni * 16 + row16;
          int t = m >> 2, bb = m & 3;
          int which = n >> 10, hh = (n >> 6) & 15, dd = n & 63;
          Cq[(size_t)(which * 64 + bb * 16 + hh) * PLANE + (size_t)t * 64 + dd] =
              f2bf(acc[mi][ni][r]);
        }
  }
}

// ---------------------------------------------------------------------------
// gemm128 (m97 structure, swizzled LDS), fp32 output — out-proj.
// ---------------------------------------------------------------------------
__global__ __launch_bounds__(256)
void gemm128(const unsigned short* __restrict__ A,
             const unsigned short* __restrict__ Bw,
             float* __restrict__ Cf, int N, int K) {
  __shared__ __attribute__((aligned(16))) unsigned short As[128 * 64];
  __shared__ __attribute__((aligned(16))) unsigned short Bs[128 * 64];

  const int tid = threadIdx.x, lane = tid & 63, w = tid >> 6;
  const int row16 = lane & 15, quad = lane >> 4;
  const int m0 = blockIdx.y * 128, n0 = blockIdx.x * 128;
  const int wm = (w & 1) * 64, wn = (w >> 1) * 64;
  const int srow = lane >> 3;
  const int jsw = (lane & 7) ^ srow;
  const int sw7 = row16 & 7;

  f32x4 acc[4][4];
  for (int i = 0; i < 4; ++i)
    for (int j = 0; j < 4; ++j) acc[i][j] = (f32x4){0.f, 0.f, 0.f, 0.f};

  for (int k0 = 0; k0 < K; k0 += 64) {
    for (int i = 0; i < 4; ++i) {
      int ia = i * 4 + w;
      int r = ia * 8 + srow;
      gl2lds16(A  + (size_t)(m0 + r) * K + k0 + jsw * 8, &As[ia * 512]);
      gl2lds16(Bw + (size_t)(n0 + r) * K + k0 + jsw * 8, &Bs[ia * 512]);
    }
    __syncthreads();
    for (int kk = 0; kk < 2; ++kk) {
      s16x8 af[4], bfr[4];
      for (int mi = 0; mi < 4; ++mi)
        af[mi] = *(const s16x8*)&As[(wm + mi * 16 + row16) * 64 +
                                    (((kk * 4 + quad) ^ sw7) * 8)];
      for (int ni = 0; ni < 4; ++ni)
        bfr[ni] = *(const s16x8*)&Bs[(wn + ni * 16 + row16) * 64 +
                                     (((kk * 4 + quad) ^ sw7) * 8)];
      for (int mi = 0; mi < 4; ++mi)
        for (int ni = 0; ni < 4; ++ni)
          acc[mi][ni] = mfma16(af[mi], bfr[ni], acc[mi][ni]);
    }
    __syncthreads();
  }

  for (int mi = 0; mi < 4; ++mi)
    for (int ni = 0; ni < 4; ++ni)
      for (int r = 0; r < 4; ++r) {
        int m = m0 + wm + mi * 16 + quad * 4 + r;
        int n = n0 + wn + ni * 16 + row16;
        Cf[(size_t)m * N + n] = acc[mi][ni][r];
      }
}

// ---------------------------------------------------------------------------
// Flash attention (round-13 version). grid = (64, 8), 512 threads (8 waves).
// ---------------------------------------------------------------------------
__global__ __launch_bounds__(512, 4)
void attn_fwd(const unsigned short* __restrict__ qkv,
              unsigned short* __restrict__ ctx) {
  __shared__ __attribute__((aligned(16))) unsigned short Ks[2][4096];
  __shared__ __attribute__((aligned(16))) unsigned short Vs[2][4096];
  __shared__ __attribute__((aligned(16))) unsigned short Ps[8][1024];

  const int tid = threadIdx.x, lane = tid & 63, w = tid >> 6;  // w 0..7
  const int row16 = lane & 15, quad = lane >> 4;
  const int bh = blockIdx.x;     // 0..63
  const int p  = blockIdx.y;     // 0..7
  const int b = bh >> 4, h = bh & 15;

  const unsigned short* Qg = qkv + (size_t)bh * PLANE;          // [t][d]
  const unsigned short* Kg = qkv + (size_t)(64 + bh) * PLANE;   // [t][d]
  const unsigned short* Vt = qkv + (size_t)(128 + bh) * PLANE;  // [d][t]

  const int r8 = lane >> 3;
  const int jsw = (lane & 7) ^ r8;
  const int sw7 = row16 & 7;

  auto stage = [&](int c, int buf) {   // 2 DMA issues per wave per call
    int r = w * 8 + r8;                // 8 waves cover all 64 rows
    gl2lds16(Kg + (size_t)(c * 64 + r) * 64 + jsw * 8, &Ks[buf][w * 512]);
    gl2lds16(Vt + (size_t)r * T_DIM + c * 64 + jsw * 8, &Vs[buf][w * 512]);
  };

  for (int half = 0; half < 2; ++half) {
    const int qt = half ? p : (15 - p);
    const int q0w = qt * 128 + w * 16;
    const int cmax = 2 * qt + 1;           // >= 1 always
    const int dc = 2 * qt + (w >> 2);

    s16x8 qb[2];
    for (int s = 0; s < 2; ++s)
      qb[s] = *(const s16x8*)(Qg + (size_t)(q0w + row16) * 64 + s * 32 +
                              quad * 8);

    f32x4 O[4];
    for (int md = 0; md < 4; ++md) O[md] = (f32x4){0.f, 0.f, 0.f, 0.f};
    float lp = 0.f;

    // 2-deep prologue (final end-of-iter barrier of prev half cleared WAR)
    stage(0, 0);
    stage(1, 1);

    for (int c = 0; c <= cmax; ++c) {
      const int buf = c & 1;
      // Counted wait: own chunk c landed; chunk c+1 stays in flight across
      // the barrier (T4 — drain to 0 only on the final iter).
      if (c < cmax) VMC(2);
      else          VMC(0);
      BAR();  // all waves' chunk c landed

      if (c <= dc) {
        f32x4 S[4];
        for (int nt = 0; nt < 4; ++nt) S[nt] = (f32x4){0.f, 0.f, 0.f, 0.f};
        __builtin_amdgcn_s_setprio(1);
        for (int nt = 0; nt < 4; ++nt)
          for (int s = 0; s < 2; ++s) {
            s16x8 ka = *(const s16x8*)&Ks[buf][(nt * 16 + row16) * 64 +
                                              (((s * 4 + quad) ^ sw7) * 8)];
            S[nt] = mfma16(ka, qb[s], S[nt]);
          }
        __builtin_amdgcn_s_setprio(0);

        // softmax numerator + pack into Ps; diag path carries the causal mask
        const int qg = q0w + row16;
        auto softmax_store = [&](bool diagm) {
          for (int nt = 0; nt < 4; ++nt) {
            float pv[4];
            for (int r = 0; r < 4; ++r) {
              pv[r] = __builtin_amdgcn_exp2f(S[nt][r]);
              if (diagm && (c * 64 + nt * 16 + quad * 4 + r) > qg) pv[r] = 0.f;
              lp += pv[r];
            }
            int pos = (nt * 2 + (quad >> 1)) ^ sw7;
            *(uint2*)&Ps[w][row16 * 64 + pos * 8 + (quad & 1) * 4] =
                make_uint2(packbf(pv[0], pv[1]), packbf(pv[2], pv[3]));
          }
        };
        if (c == dc) softmax_store(true); else softmax_store(false);
        LGKM0();  // Ps is per-wave

        __builtin_amdgcn_s_setprio(1);
        for (int sk = 0; sk < 2; ++sk) {
          s16x8 pb = *(const s16x8*)&Ps[w][row16 * 64 +
                                          (((sk * 4 + quad) ^ sw7) * 8)];
          for (int md = 0; md < 4; ++md) {
            s16x8 va = *(const s16x8*)&Vs[buf][(md * 16 + row16) * 64 +
                                              (((sk * 4 + quad) ^ sw7) * 8)];
            O[md] = mfma16(va, pb, O[md]);
          }
        }
        __builtin_amdgcn_s_setprio(0);
      }

      BAR();  // all waves done reading buf -> WAR clear
      if (c + 2 <= cmax) stage(c + 2, buf);
    }

    {
      float s = lp;
      s += __shfl_xor(s, 16);
      s += __shfl_xor(s, 32);
      float inv = 1.f / s;
      const int t = q0w + row16;
      for (int md = 0; md < 4; ++md) {
        unsigned lo = packbf(O[md][0] * inv, O[md][1] * inv);
        unsigned hi = packbf(O[md][2] * inv, O[md][3] * inv);
        *(uint2*)&ctx[((size_t)t * B_DIM + b) * E_DIM + h * 64 + md * 16 +
                      quad * 4] = make_uint2(lo, hi);
      }
    }
  }
}

// ---------------------------------------------------------------------------
extern "C" void kernel_launch(void* const* d_in, const int* in_sizes, int n_in,
                              void* d_out, int out_size, void* d_ws,
                              size_t ws_size, hipStream_t stream) {
  const float* query = (const float*)d_in[0];  // [T,B,E] = [8192,1024]
  const float* win   = (const float*)d_in[1];  // [3072,1024]
  const float* wout  = (const float*)d_in[2];  // [1024,1024]
  float* out = (float*)d_out;

  const size_t qkv_el = (size_t)3 * 64 * PLANE;   // 25,165,824 ushort
  const size_t ctx_el = (size_t)T_DIM * B_DIM * E_DIM;  // 8,388,608 ushort

  unsigned short* qkvb = (unsigned short*)d_ws;
  unsigned short* ctxb = qkvb + qkv_el;
  unsigned short* xb   = ctxb;                   // dies before ctx written
  unsigned short* winb = (unsigned short*)d_out; // d_out scratch until gemm2

  // W_out bf16: fresh ws region after ctx when it fits (enables upfront
  // merged cvt); else reuse qkvb after attn (old path).
  const bool big_ws = ws_size >= (qkv_el + ctx_el + (size_t)E_DIM * E_DIM) * 2;
  unsigned short* woutb = big_ws ? (ctxb + ctx_el) : qkvb;

  // 0.125 (1/sqrt(D)) * log2(e): folded into W_q so attn uses exp2 directly.
  const float QSCALE = 0.18033688011112042f;

  cvt_all<<<big_ws ? 12288 : 11264, 256, 0, stream>>>(
      query, win, wout, xb, winb, woutb, QSCALE, big_ws ? 1 : 0);
  gemm_qkv<<<dim3(3072 / 128, 8192 / 128), 256, 0, stream>>>(xb, winb, qkvb,
                                                             1024);
  attn_fwd<<<dim3(64, 8), 512, 0, stream>>>(qkvb, ctxb);
  if (!big_ws)
    cvt_bf16<<<1024, 256, 0, stream>>>(wout, woutb, (1024 * 1024) / 4);
  gemm128<<<dim3(8, 64), 256, 0, stream>>>(ctxb, woutb, out, 1024, 1024);
}

// Round 12
// 227.195 us; speedup vs baseline: 1.0243x; 1.0005x over previous
//
#include <hip/hip_runtime.h>

// ---------------------------------------------------------------------------
// SelfMultiheadAttn fwd: T=2048, B=4, E=1024, H=16, D=64, causal.
// Round 20:
//  * gemm_qkv -> 512 threads / 8 waves (attn round-12 pattern: fixed grid +
//    more waves/block). Wave slice 32m x 64n (wm=(w&3)*32, wn=(w>>2)*64),
//    acc[2][4], 16 MFMA/iter. Staging 4 DMA/wave -> VMC(4) mid / VMC(0)
//    final. LDS 64KB dbuf -> 2 blocks/CU = 16 waves/CU (was 8). Grid 1536 =
//    3 uniform co-residency rounds. Epilogues re-derived: Q/K scatter (mi<2,
//    same algebra), V-transpose 64dd x 8t per wave (stride-12, one 16B
//    store/lane/bb).
//  * gemm128 gets the identical dbuf + counted-vmcnt K-loop (r19 template).
// Round-19 verified: dbuf+VMC(8) took gemm_qkv 75.2->64.3, MfmaUtil 32.
// Kept: attn 8-wave counted-vmcnt (r13), merged cvt, exp2 W_q fold.
// ---------------------------------------------------------------------------

typedef float  f32x4  __attribute__((ext_vector_type(4)));
typedef short  s16x8  __attribute__((ext_vector_type(8)));
typedef __bf16 bf16x8 __attribute__((ext_vector_type(8)));

#define T_DIM 2048
#define B_DIM 4
#define E_DIM 1024
#define PLANE (T_DIM * 64)   // elements per (which,b,h) plane

#define VMC(N) asm volatile("s_waitcnt vmcnt(" #N ")" ::: "memory")
#define LGKM0() asm volatile("s_waitcnt lgkmcnt(0)" ::: "memory")
#define BAR() __builtin_amdgcn_s_barrier()

__device__ inline unsigned short f2bf(float f) {
  return (unsigned short)((__builtin_bit_cast(unsigned int, f) + 0x8000u) >> 16);
}

__device__ inline f32x4 mfma16(s16x8 a, s16x8 b, f32x4 c) {
  return __builtin_amdgcn_mfma_f32_16x16x32_bf16(
      __builtin_bit_cast(bf16x8, a), __builtin_bit_cast(bf16x8, b), c, 0, 0, 0);
}

__device__ inline void gl2lds16(const unsigned short* g, unsigned short* l) {
  __builtin_amdgcn_global_load_lds(
      (__attribute__((address_space(1))) unsigned int*)g,
      (__attribute__((address_space(3))) unsigned int*)l, 16, 0, 0);
}

// pack hi16(a) | hi16(b)<<16  (bf16 truncation) in one v_perm
__device__ inline unsigned packbf(float a, float b) {
  return __builtin_amdgcn_perm(__builtin_bit_cast(unsigned, b),
                               __builtin_bit_cast(unsigned, a), 0x07060302u);
}

// ---------------------------------------------------------------------------
// Merged input conversion: blocks [0,8192) query -> xb; [8192,11264) W_in ->
// winb (first E*E/4 float4s carry the Q scale); [11264,12288) W_out -> wob
// (skipped when do_wout==0; fallback path converts W_out after attn).
// ---------------------------------------------------------------------------
__global__ __launch_bounds__(256)
void cvt_all(const float* __restrict__ q, const float* __restrict__ wi,
             const float* __restrict__ wo, unsigned short* __restrict__ xb,
             unsigned short* __restrict__ wib, unsigned short* __restrict__ wob,
             float qs, int do_wout) {
  int blk = blockIdx.x;
  const float* src;
  unsigned short* dst;
  int i;
  float sc = 1.0f;
  if (blk < 8192) {
    src = q; dst = xb; i = blk * 256 + threadIdx.x;
  } else if (blk < 11264) {
    src = wi; dst = wib; i = (blk - 8192) * 256 + threadIdx.x;
    if (i < (E_DIM * E_DIM / 4)) sc = qs;
  } else {
    if (!do_wout) return;
    src = wo; dst = wob; i = (blk - 11264) * 256 + threadIdx.x;
  }
  float4 v = ((const float4*)src)[i];
  ushort4 o;
  o.x = f2bf(v.x * sc); o.y = f2bf(v.y * sc);
  o.z = f2bf(v.z * sc); o.w = f2bf(v.w * sc);
  ((ushort4*)dst)[i] = o;
}

__global__ __launch_bounds__(256)
void cvt_bf16(const float* __restrict__ in, unsigned short* __restrict__ out,
              int n4) {
  int i = blockIdx.x * 256 + threadIdx.x;
  if (i >= n4) return;
  float4 v = ((const float4*)in)[i];
  ushort4 o;
  o.x = f2bf(v.x); o.y = f2bf(v.y); o.z = f2bf(v.z); o.w = f2bf(v.w);
  ((ushort4*)out)[i] = o;
}

// ---------------------------------------------------------------------------
// gemm_qkv: C[m,n]=sum_k A[m,k]*B[n,k]; 128x128 tile, 512 thr / 8 waves,
// dbuf + counted vmcnt. Epilogue -> qkv scatter; V via per-wave transpose.
// ---------------------------------------------------------------------------
__global__ __launch_bounds__(512, 4)
void gemm_qkv(const unsigned short* __restrict__ A,
              const unsigned short* __restrict__ Bw,
              unsigned short* __restrict__ Cq, int K) {
  __shared__ __attribute__((aligned(16))) unsigned short As[2][8192];
  __shared__ __attribute__((aligned(16))) unsigned short Bs[2][8192];

  const int tid = threadIdx.x, lane = tid & 63, w = tid >> 6;  // w 0..7
  const int row16 = lane & 15, quad = lane >> 4;
  const int m0 = blockIdx.y * 128, n0 = blockIdx.x * 128;
  const int wm = (w & 3) * 32, wn = (w >> 2) * 64;
  const int srow = lane >> 3;
  const int jsw = (lane & 7) ^ srow;
  const int sw7 = row16 & 7;

  f32x4 acc[2][4];
  for (int i = 0; i < 2; ++i)
    for (int j = 0; j < 4; ++j) acc[i][j] = (f32x4){0.f, 0.f, 0.f, 0.f};

  auto stage = [&](int kt, int buf) {   // 4 DMA issues per wave
#pragma unroll
    for (int i = 0; i < 2; ++i) {
      int ia = w * 2 + i;               // 0..15, covers 128 rows x8
      int r = ia * 8 + srow;
      gl2lds16(A  + (size_t)(m0 + r) * K + kt * 64 + jsw * 8,
               &As[buf][ia * 512]);
      gl2lds16(Bw + (size_t)(n0 + r) * K + kt * 64 + jsw * 8,
               &Bs[buf][ia * 512]);
    }
  };

  const int NT = K / 64;  // 16 K-tiles
  stage(0, 0);
  stage(1, 1);

  for (int kt = 0; kt < NT; ++kt) {
    const int buf = kt & 1;
    // tile kt's 4 loads landed; tile kt+1's 4 stay in flight (T4).
    if (kt < NT - 1) VMC(4);
    else             VMC(0);
    BAR();

    for (int kk = 0; kk < 2; ++kk) {
      s16x8 af[2], bfr[4];
      for (int mi = 0; mi < 2; ++mi)
        af[mi] = *(const s16x8*)&As[buf][(wm + mi * 16 + row16) * 64 +
                                         (((kk * 4 + quad) ^ sw7) * 8)];
      for (int ni = 0; ni < 4; ++ni)
        bfr[ni] = *(const s16x8*)&Bs[buf][(wn + ni * 16 + row16) * 64 +
                                          (((kk * 4 + quad) ^ sw7) * 8)];
      __builtin_amdgcn_s_setprio(1);
      for (int mi = 0; mi < 2; ++mi)
        for (int ni = 0; ni < 4; ++ni)
          acc[mi][ni] = mfma16(af[mi], bfr[ni], acc[mi][ni]);
      __builtin_amdgcn_s_setprio(0);
    }

    BAR();  // all waves done reading buf -> WAR clear
    if (kt + 2 < NT) stage(kt + 2, buf);
  }

  if (n0 >= 2048) {
    // V block. Wave w: head hw = ((n0-2048)>>6) + (w>>2); 32 m-rows =
    // 8 t x 4 b, t-base tg0 = m0/4 + (w&3)*8. tb[64 dd][8 tl], stride 12.
    const int hw = ((n0 - 2048) >> 6) + (w >> 2);
    const int tg0 = (m0 >> 2) + (w & 3) * 8;
    unsigned short* tb = &As[0][0] + w * 768;   // 64*12 = 768/wave, 12KB total
    for (int bb = 0; bb < 4; ++bb) {
#pragma unroll
      for (int mi = 0; mi < 2; ++mi)
#pragma unroll
        for (int ni = 0; ni < 4; ++ni)
          tb[(ni * 16 + row16) * 12 + mi * 4 + quad] = f2bf(acc[mi][ni][bb]);
      LGKM0();
      unsigned short* vp = Cq + (size_t)(128 + bb * 16 + hw) * PLANE;
      {
        int dd = lane;                      // one 16B store per lane
        s16x8 v = *(const s16x8*)&tb[dd * 12];
        *(s16x8*)(vp + (size_t)dd * T_DIM + tg0) = v;
      }
      LGKM0();  // WAR before next bb overwrites tb
    }
  } else {
    // Q/K blocks: [t][d] scatter (32B runs across row16 lanes)
    for (int mi = 0; mi < 2; ++mi)
      for (int ni = 0; ni < 4; ++ni)
        for (int r = 0; r < 4; ++r) {
          int m = m0 + wm + mi * 16 + quad * 4 + r;
          int n = n0 + wn + ni * 16 + row16;
          int t = m >> 2, bb = m & 3;
          int which = n >> 10, hh = (n >> 6) & 15, dd = n & 63;
          Cq[(size_t)(which * 64 + bb * 16 + hh) * PLANE + (size_t)t * 64 + dd] =
              f2bf(acc[mi][ni][r]);
        }
  }
}

// ---------------------------------------------------------------------------
// gemm128: out-proj, fp32 output; dbuf + counted vmcnt (r19 template).
// ---------------------------------------------------------------------------
__global__ __launch_bounds__(256)
void gemm128(const unsigned short* __restrict__ A,
             const unsigned short* __restrict__ Bw,
             float* __restrict__ Cf, int N, int K) {
  __shared__ __attribute__((aligned(16))) unsigned short As[2][8192];
  __shared__ __attribute__((aligned(16))) unsigned short Bs[2][8192];

  const int tid = threadIdx.x, lane = tid & 63, w = tid >> 6;
  const int row16 = lane & 15, quad = lane >> 4;
  const int m0 = blockIdx.y * 128, n0 = blockIdx.x * 128;
  const int wm = (w & 1) * 64, wn = (w >> 1) * 64;
  const int srow = lane >> 3;
  const int jsw = (lane & 7) ^ srow;
  const int sw7 = row16 & 7;

  f32x4 acc[4][4];
  for (int i = 0; i < 4; ++i)
    for (int j = 0; j < 4; ++j) acc[i][j] = (f32x4){0.f, 0.f, 0.f, 0.f};

  auto stage = [&](int kt, int buf) {   // 8 DMA issues per wave
#pragma unroll
    for (int i = 0; i < 4; ++i) {
      int ia = i * 4 + w;
      int r = ia * 8 + srow;
      gl2lds16(A  + (size_t)(m0 + r) * K + kt * 64 + jsw * 8,
               &As[buf][ia * 512]);
      gl2lds16(Bw + (size_t)(n0 + r) * K + kt * 64 + jsw * 8,
               &Bs[buf][ia * 512]);
    }
  };

  const int NT = K / 64;
  stage(0, 0);
  stage(1, 1);

  for (int kt = 0; kt < NT; ++kt) {
    const int buf = kt & 1;
    if (kt < NT - 1) VMC(8);
    else             VMC(0);
    BAR();

    for (int kk = 0; kk < 2; ++kk) {
      s16x8 af[4], bfr[4];
      for (int mi = 0; mi < 4; ++mi)
        af[mi] = *(const s16x8*)&As[buf][(wm + mi * 16 + row16) * 64 +
                                         (((kk * 4 + quad) ^ sw7) * 8)];
      for (int ni = 0; ni < 4; ++ni)
        bfr[ni] = *(const s16x8*)&Bs[buf][(wn + ni * 16 + row16) * 64 +
                                          (((kk * 4 + quad) ^ sw7) * 8)];
      for (int mi = 0; mi < 4; ++mi)
        for (int ni = 0; ni < 4; ++ni)
          acc[mi][ni] = mfma16(af[mi], bfr[ni], acc[mi][ni]);
    }

    BAR();
    if (kt + 2 < NT) stage(kt + 2, buf);
  }

  for (int mi = 0; mi < 4; ++mi)
    for (int ni = 0; ni < 4; ++ni)
      for (int r = 0; r < 4; ++r) {
        int m = m0 + wm + mi * 16 + quad * 4 + r;
        int n = n0 + wn + ni * 16 + row16;
        Cf[(size_t)m * N + n] = acc[mi][ni][r];
      }
}

// ---------------------------------------------------------------------------
// Flash attention (round-13 version). grid = (64, 8), 512 threads (8 waves).
// ---------------------------------------------------------------------------
__global__ __launch_bounds__(512, 4)
void attn_fwd(const unsigned short* __restrict__ qkv,
              unsigned short* __restrict__ ctx) {
  __shared__ __attribute__((aligned(16))) unsigned short Ks[2][4096];
  __shared__ __attribute__((aligned(16))) unsigned short Vs[2][4096];
  __shared__ __attribute__((aligned(16))) unsigned short Ps[8][1024];

  const int tid = threadIdx.x, lane = tid & 63, w = tid >> 6;  // w 0..7
  const int row16 = lane & 15, quad = lane >> 4;
  const int bh = blockIdx.x;     // 0..63
  const int p  = blockIdx.y;     // 0..7
  const int b = bh >> 4, h = bh & 15;

  const unsigned short* Qg = qkv + (size_t)bh * PLANE;          // [t][d]
  const unsigned short* Kg = qkv + (size_t)(64 + bh) * PLANE;   // [t][d]
  const unsigned short* Vt = qkv + (size_t)(128 + bh) * PLANE;  // [d][t]

  const int r8 = lane >> 3;
  const int jsw = (lane & 7) ^ r8;
  const int sw7 = row16 & 7;

  auto stage = [&](int c, int buf) {   // 2 DMA issues per wave per call
    int r = w * 8 + r8;                // 8 waves cover all 64 rows
    gl2lds16(Kg + (size_t)(c * 64 + r) * 64 + jsw * 8, &Ks[buf][w * 512]);
    gl2lds16(Vt + (size_t)r * T_DIM + c * 64 + jsw * 8, &Vs[buf][w * 512]);
  };

  for (int half = 0; half < 2; ++half) {
    const int qt = half ? p : (15 - p);
    const int q0w = qt * 128 + w * 16;
    const int cmax = 2 * qt + 1;           // >= 1 always
    const int dc = 2 * qt + (w >> 2);

    s16x8 qb[2];
    for (int s = 0; s < 2; ++s)
      qb[s] = *(const s16x8*)(Qg + (size_t)(q0w + row16) * 64 + s * 32 +
                              quad * 8);

    f32x4 O[4];
    for (int md = 0; md < 4; ++md) O[md] = (f32x4){0.f, 0.f, 0.f, 0.f};
    float lp = 0.f;

    // 2-deep prologue (final end-of-iter barrier of prev half cleared WAR)
    stage(0, 0);
    stage(1, 1);

    for (int c = 0; c <= cmax; ++c) {
      const int buf = c & 1;
      // Counted wait: own chunk c landed; chunk c+1 stays in flight across
      // the barrier (T4 — drain to 0 only on the final iter).
      if (c < cmax) VMC(2);
      else          VMC(0);
      BAR();  // all waves' chunk c landed

      if (c <= dc) {
        f32x4 S[4];
        for (int nt = 0; nt < 4; ++nt) S[nt] = (f32x4){0.f, 0.f, 0.f, 0.f};
        __builtin_amdgcn_s_setprio(1);
        for (int nt = 0; nt < 4; ++nt)
          for (int s = 0; s < 2; ++s) {
            s16x8 ka = *(const s16x8*)&Ks[buf][(nt * 16 + row16) * 64 +
                                              (((s * 4 + quad) ^ sw7) * 8)];
            S[nt] = mfma16(ka, qb[s], S[nt]);
          }
        __builtin_amdgcn_s_setprio(0);

        // softmax numerator + pack into Ps; diag path carries the causal mask
        const int qg = q0w + row16;
        auto softmax_store = [&](bool diagm) {
          for (int nt = 0; nt < 4; ++nt) {
            float pv[4];
            for (int r = 0; r < 4; ++r) {
              pv[r] = __builtin_amdgcn_exp2f(S[nt][r]);
              if (diagm && (c * 64 + nt * 16 + quad * 4 + r) > qg) pv[r] = 0.f;
              lp += pv[r];
            }
            int pos = (nt * 2 + (quad >> 1)) ^ sw7;
            *(uint2*)&Ps[w][row16 * 64 + pos * 8 + (quad & 1) * 4] =
                make_uint2(packbf(pv[0], pv[1]), packbf(pv[2], pv[3]));
          }
        };
        if (c == dc) softmax_store(true); else softmax_store(false);
        LGKM0();  // Ps is per-wave

        __builtin_amdgcn_s_setprio(1);
        for (int sk = 0; sk < 2; ++sk) {
          s16x8 pb = *(const s16x8*)&Ps[w][row16 * 64 +
                                          (((sk * 4 + quad) ^ sw7) * 8)];
          for (int md = 0; md < 4; ++md) {
            s16x8 va = *(const s16x8*)&Vs[buf][(md * 16 + row16) * 64 +
                                              (((sk * 4 + quad) ^ sw7) * 8)];
            O[md] = mfma16(va, pb, O[md]);
          }
        }
        __builtin_amdgcn_s_setprio(0);
      }

      BAR();  // all waves done reading buf -> WAR clear
      if (c + 2 <= cmax) stage(c + 2, buf);
    }

    {
      float s = lp;
      s += __shfl_xor(s, 16);
      s += __shfl_xor(s, 32);
      float inv = 1.f / s;
      const int t = q0w + row16;
      for (int md = 0; md < 4; ++md) {
        unsigned lo = packbf(O[md][0] * inv, O[md][1] * inv);
        unsigned hi = packbf(O[md][2] * inv, O[md][3] * inv);
        *(uint2*)&ctx[((size_t)t * B_DIM + b) * E_DIM + h * 64 + md * 16 +
                      quad * 4] = make_uint2(lo, hi);
      }
    }
  }
}

// ---------------------------------------------------------------------------
extern "C" void kernel_launch(void* const* d_in, const int* in_sizes, int n_in,
                              void* d_out, int out_size, void* d_ws,
                              size_t ws_size, hipStream_t stream) {
  const float* query = (const float*)d_in[0];  // [T,B,E] = [8192,1024]
  const float* win   = (const float*)d_in[1];  // [3072,1024]
  const float* wout  = (const float*)d_in[2];  // [1024,1024]
  float* out = (float*)d_out;

  const size_t qkv_el = (size_t)3 * 64 * PLANE;   // 25,165,824 ushort
  const size_t ctx_el = (size_t)T_DIM * B_DIM * E_DIM;  // 8,388,608 ushort

  unsigned short* qkvb = (unsigned short*)d_ws;
  unsigned short* ctxb = qkvb + qkv_el;
  unsigned short* xb   = ctxb;                   // dies before ctx written
  unsigned short* winb = (unsigned short*)d_out; // d_out scratch until gemm2

  // W_out bf16: fresh ws region after ctx when it fits (enables upfront
  // merged cvt); else reuse qkvb after attn (old path).
  const bool big_ws = ws_size >= (qkv_el + ctx_el + (size_t)E_DIM * E_DIM) * 2;
  unsigned short* woutb = big_ws ? (ctxb + ctx_el) : qkvb;

  // 0.125 (1/sqrt(D)) * log2(e): folded into W_q so attn uses exp2 directly.
  const float QSCALE = 0.18033688011112042f;

  cvt_all<<<big_ws ? 12288 : 11264, 256, 0, stream>>>(
      query, win, wout, xb, winb, woutb, QSCALE, big_ws ? 1 : 0);
  gemm_qkv<<<dim3(3072 / 128, 8192 / 128), 512, 0, stream>>>(xb, winb, qkvb,
                                                             1024);
  attn_fwd<<<dim3(64, 8), 512, 0, stream>>>(qkvb, ctxb);
  if (!big_ws)
    cvt_bf16<<<1024, 256, 0, stream>>>(wout, woutb, (1024 * 1024) / 4);
  gemm128<<<dim3(8, 64), 256, 0, stream>>>(ctxb, woutb, out, 1024, 1024);
}